// Round 13
// baseline (21150.525 us; speedup 1.0000x reference)
//
#include <hip/hip_runtime.h>
#include <hip/hip_bf16.h>
#include <stdint.h>

// Problem constants
#define HD   1024
#define BB   32
#define TT   512
#define LL   3
#define H3   3072
#define MTOT (BB*TT)   // 16384

#define PLSZ 32768     // u16 per h plane: 128 kc x 32 b x 8
#define WSL3 49152     // u16 per pad-free slab: 128 kc x 48 j x 8 (j = gate*16+u)

typedef unsigned short u16;
typedef short bf16x8 __attribute__((ext_vector_type(8)));
typedef float f32x4 __attribute__((ext_vector_type(4)));

__device__ __forceinline__ u16 f2bf_bits(float f) {
    __hip_bfloat16 h = __float2bfloat16(f);   // RNE
    return __builtin_bit_cast(u16, h);
}
__device__ __forceinline__ float bf_bits2f(u16 b) {
    return __bfloat162float(__builtin_bit_cast(__hip_bfloat16, b));
}

// 8 consecutive fp32 -> bf16 hi/lo fragments
__device__ __forceinline__ void split8(const f32x4 v0, const f32x4 v1,
                                       bf16x8& hi, bf16x8& lo) {
#pragma unroll
    for (int e = 0; e < 4; ++e) {
        u16 h = f2bf_bits(v0[e]);
        hi[e] = (short)h;
        lo[e] = (short)f2bf_bits(v0[e] - bf_bits2f(h));
        u16 h2 = f2bf_bits(v1[e]);
        hi[4 + e] = (short)h2;
        lo[4 + e] = (short)f2bf_bits(v1[e] - bf_bits2f(h2));
    }
}

// ---------------------------------------------------------------------------
// Split fp32 -> (hi, lo) bf16 planes (row-major, for the big GEMM)
__global__ void split_f32_kernel(const float* __restrict__ in,
                                 u16* __restrict__ hi, u16* __restrict__ lo, int n4) {
    int i = blockIdx.x * blockDim.x + threadIdx.x;
    int stride = gridDim.x * blockDim.x;
    for (; i < n4; i += stride) {
        float4 v = ((const float4*)in)[i];
        ushort4 h, l;
        float f;
        f = v.x; h.x = f2bf_bits(f); l.x = f2bf_bits(f - bf_bits2f(h.x));
        f = v.y; h.y = f2bf_bits(f); l.y = f2bf_bits(f - bf_bits2f(h.y));
        f = v.z; h.z = f2bf_bits(f); l.z = f2bf_bits(f - bf_bits2f(h.z));
        f = v.w; h.w = f2bf_bits(f); l.w = f2bf_bits(f - bf_bits2f(h.w));
        ((ushort4*)hi)[i] = h;
        ((ushort4*)lo)[i] = l;
    }
}

// fp32 -> bf16 (hi only)
__global__ void tobf_kernel(const float* __restrict__ in, u16* __restrict__ out, int n4) {
    int i = blockIdx.x * blockDim.x + threadIdx.x;
    int stride = gridDim.x * blockDim.x;
    for (; i < n4; i += stride) {
        float4 v = ((const float4*)in)[i];
        ushort4 h;
        h.x = f2bf_bits(v.x); h.y = f2bf_bits(v.y);
        h.z = f2bf_bits(v.z); h.w = f2bf_bits(v.w);
        ((ushort4*)out)[i] = h;
    }
}

// ---------------------------------------------------------------------------
// Pack per-(layer, ug64) pad-free slabs in fragment order [kc][48][8],
// j = gate*16 + u (48 rows = exactly 3 16-row fragments, no padding).
__global__ __launch_bounds__(256) void pack_w_kernel(
    const float* __restrict__ whh, const float* __restrict__ wih,
    u16* __restrict__ wslab, u16* __restrict__ wislab)
{
    const int l  = blockIdx.x >> 6;          // 0..2
    const int ug = blockIdx.x & 63;          // 0..63
    const int n0 = ug * 16;
    const int tid = threadIdx.x;
    const int jr = tid >> 4, c16 = tid & 15;
    const float* wh = whh + (size_t)l * H3 * HD;
    const float* wi = wih + (size_t)l * H3 * HD;
    u16* dh = wslab + ((size_t)l * 64 + ug) * WSL3;
    u16* di = (l > 0) ? (wislab + ((size_t)(l - 1) * 64 + ug) * WSL3) : (u16*)nullptr;
#pragma unroll
    for (int jj = 0; jj < 3; ++jj) {
        int j = jj * 16 + jr;                // 0..47
        int gate = j >> 4, u = j & 15;
        const size_t rowoff = ((size_t)gate * HD + n0 + u) * HD;
#pragma unroll
        for (int c = 0; c < 8; ++c) {
            int kc = c16 + c * 16;
            f32x4 v0 = *(const f32x4*)(wh + rowoff + kc * 8);
            f32x4 v1 = *(const f32x4*)(wh + rowoff + kc * 8 + 4);
            bf16x8 hi, lo;
            split8(v0, v1, hi, lo);
            *(bf16x8*)(dh + ((size_t)kc * 48 + j) * 8) = hi;
            if (l > 0) {
                f32x4 u0 = *(const f32x4*)(wi + rowoff + kc * 8);
                f32x4 u1 = *(const f32x4*)(wi + rowoff + kc * 8 + 4);
                bf16x8 ihi, dum;
                split8(u0, u1, ihi, dum);
                *(bf16x8*)(di + ((size_t)kc * 48 + j) * 8) = ihi;
            }
        }
    }
}

// h0 -> fp32 ping-pong (parity 0) + transposed bf16 hi/lo planes (parity 0)
__global__ void pack_h0_kernel(const float* __restrict__ h0,
                               float* __restrict__ hb, u16* __restrict__ ht) {
    int idx = blockIdx.x * 256 + threadIdx.x;   // 3*32*1024 total
    int l = idx >> 15;
    int rem = idx & 32767;
    int b = rem >> 10, n = rem & 1023;
    float f = h0[idx];
    hb[(size_t)(l * 2) * BB * HD + rem] = f;
    u16 hbits = f2bf_bits(f);
    u16 lbits = f2bf_bits(f - bf_bits2f(hbits));
    size_t o = ((size_t)(l * 2) * 2) * PLSZ + ((size_t)(n >> 3) * 32 + b) * 8 + (n & 7);
    ht[o] = hbits;
    ht[o + PLSZ] = lbits;
}

// ---------------------------------------------------------------------------
// 2-pass split-A bf16 MFMA GEMM (layer-0 input projections) — unchanged, proven.
#define BM 128
#define BN 128
#define BK 32
#define LDSROW 40

__global__ __launch_bounds__(256) void gemm2p_kernel(
    const u16* __restrict__ Ahi, const u16* __restrict__ Alo,
    const u16* __restrict__ Wn,
    const float* __restrict__ bias,
    u16* __restrict__ Cout)
{
    __shared__ u16 sAh[BM * LDSROW];
    __shared__ u16 sAl[BM * LDSROW];
    __shared__ u16 sB [BN * LDSROW];

    const int tid  = threadIdx.x;
    const int lane = tid & 63;
    const int w    = tid >> 6;
    const int wr   = w >> 1, wc = w & 1;
    const int fr   = lane & 15;
    const int kg   = lane >> 4;

    const int bm = blockIdx.x & 127;
    const int bn = blockIdx.x >> 7;
    const int bmBase = bm * BM;
    const int bnBase = bn * BN;

    f32x4 acc[4][4] = {};

    for (int kt = 0; kt < 1024; kt += BK) {
        uint4 ra[2], rl[2], rb[2];
#pragma unroll
        for (int it = 0; it < 2; ++it) {
            int c = it * 256 + tid;
            int row = c >> 2, seg = c & 3;
            size_t ga = (size_t)(bmBase + row) * 1024 + kt + seg * 8;
            ra[it] = *(const uint4*)(Ahi + ga);
            rl[it] = *(const uint4*)(Alo + ga);
            size_t gb = (size_t)(bnBase + row) * 1024 + kt + seg * 8;
            rb[it] = *(const uint4*)(Wn + gb);
        }
        __syncthreads();
#pragma unroll
        for (int it = 0; it < 2; ++it) {
            int c = it * 256 + tid;
            int row = c >> 2, seg = c & 3;
            int lo = row * LDSROW + seg * 8;
            *(uint4*)(sAh + lo) = ra[it];
            *(uint4*)(sAl + lo) = rl[it];
            *(uint4*)(sB  + lo) = rb[it];
        }
        __syncthreads();

        bf16x8 fah[4], fal[4], fb[4];
#pragma unroll
        for (int mi = 0; mi < 4; ++mi) {
            int r = wr * 64 + mi * 16 + fr;
            fah[mi] = *(const bf16x8*)(sAh + r * LDSROW + kg * 8);
            fal[mi] = *(const bf16x8*)(sAl + r * LDSROW + kg * 8);
        }
#pragma unroll
        for (int ni = 0; ni < 4; ++ni) {
            int r = wc * 64 + ni * 16 + fr;
            fb[ni] = *(const bf16x8*)(sB + r * LDSROW + kg * 8);
        }
#pragma unroll
        for (int mi = 0; mi < 4; ++mi)
#pragma unroll
            for (int ni = 0; ni < 4; ++ni) {
                acc[mi][ni] = __builtin_amdgcn_mfma_f32_16x16x32_bf16(fah[mi], fb[ni], acc[mi][ni], 0, 0, 0);
                acc[mi][ni] = __builtin_amdgcn_mfma_f32_16x16x32_bf16(fal[mi], fb[ni], acc[mi][ni], 0, 0, 0);
            }
    }

#pragma unroll
    for (int mi = 0; mi < 4; ++mi)
#pragma unroll
        for (int ni = 0; ni < 4; ++ni) {
            int n = bnBase + wc * 64 + ni * 16 + fr;
            float bv = bias[n];
#pragma unroll
            for (int r = 0; r < 4; ++r) {
                int m = bmBase + wr * 64 + mi * 16 + kg * 4 + r;
                int b_ = m >> 9, t_ = m & 511;           // m = b*512 + t
                Cout[(size_t)(t_ * BB + b_) * H3 + n] = f2bf_bits(acc[mi][ni][r] + bv);
            }
        }
}

// ---------------------------------------------------------------------------
// Pipelined per-step kernel. Kernel k: layer0 step k, layer1 k-1, layer2 k-2.
// Grid 192 = 3 layers x 64 ug (16 units; 48 weight rows = 3 pad-free frags);
// 512 threads = 8 waves (K-split 128 each). 4x fewer blocks than R12 cuts the
// redundant h-plane L2 re-reads 164->41 MB/step (every block needs full K).
// K-partials merged via LDS atomics (R7-proven); gate = 512 thr (32b x 16u).
#define SGRID 192

__global__ __launch_bounds__(512, 2) void gru_step_kernel(
    const u16* __restrict__ wslab,   // [3][64][WSL3] whh hi
    const u16* __restrict__ wislab,  // [2][64][WSL3] wih hi (layers 1,2)
    const float* __restrict__ bih, const float* __restrict__ bhh,  // [L][3H]
    const u16* __restrict__ gi0,     // [T][B][3H] (layer0, incl b_ih)
    float* __restrict__ hb,          // [3][2][32][1024] fp32
    u16* __restrict__ ht,            // [3][2][2][PLSZ] transposed planes
    float* __restrict__ seqout, float* __restrict__ hnout, int k)
{
    const int layer = blockIdx.x >> 6;
    const int t = k - layer;
    if (t < 0 || t >= TT) return;
    const int ug = blockIdx.x & 63;
    const int n0 = ug * 16;
    const int tid = threadIdx.x, lane = tid & 63, w = tid >> 6;
    const int arow = lane & 15, akg = lane >> 4;

    __shared__ float Cp[2][3][2][16][16];   // [src][gate][m][brow][ucol] 12KB

    // zero Cp (6 floats per thread)
#pragma unroll
    for (int z = 0; z < 6; ++z)
        ((float*)Cp)[tid + z * 512] = 0.f;

    const int xl = (layer > 0) ? layer - 1 : 0;
    const u16* hsH = ht + ((size_t)(layer * 2 + (t & 1)) * 2) * PLSZ;
    const u16* hsL = hsH + PLSZ;
    const u16* xsH = ht + ((size_t)(xl * 2 + ((t + 1) & 1)) * 2) * PLSZ;
    const u16* xsL = xsH + PLSZ;
    const u16* whH = wslab + ((size_t)layer * 64 + ug) * WSL3;
    const u16* wiH = wislab + ((size_t)xl * 64 + ug) * WSL3;

    // layer-0 gi early loads (one (b,u) per thread; latency hides under MFMAs)
    float gi_0 = 0.f, gi_1 = 0.f, gi_2 = 0.f;
    if (layer == 0) {
        const u16* gp = gi0 + (size_t)(t * BB + (tid >> 4)) * H3 + n0 + (tid & 15);
        gi_0 = bf_bits2f(gp[0]);
        gi_1 = bf_bits2f(gp[HD]);
        gi_2 = bf_bits2f(gp[2 * HD]);
    }
    __syncthreads();   // Cp zeros visible

    f32x4 agh[3][2] = {};
    f32x4 agx[3][2] = {};

#pragma unroll
    for (int kt = 0; kt < 4; ++kt) {
        const int kc = w * 16 + kt * 4 + akg;
        const int aoff = (kc * 32 + arow) * 8;     // m=0; m=1 at +128
        bf16x8 a0h = *(const bf16x8*)(hsH + aoff);
        bf16x8 a0l = *(const bf16x8*)(hsL + aoff);
        bf16x8 a1h = *(const bf16x8*)(hsH + aoff + 128);
        bf16x8 a1l = *(const bf16x8*)(hsL + aoff + 128);
        bf16x8 bh[3], bi[3];
#pragma unroll
        for (int nt = 0; nt < 3; ++nt)
            bh[nt] = *(const bf16x8*)(whH + ((size_t)kc * 48 + nt * 16 + arow) * 8);
#pragma unroll
        for (int nt = 0; nt < 3; ++nt) {
            agh[nt][0] = __builtin_amdgcn_mfma_f32_16x16x32_bf16(a0h, bh[nt], agh[nt][0], 0, 0, 0);
            agh[nt][0] = __builtin_amdgcn_mfma_f32_16x16x32_bf16(a0l, bh[nt], agh[nt][0], 0, 0, 0);
            agh[nt][1] = __builtin_amdgcn_mfma_f32_16x16x32_bf16(a1h, bh[nt], agh[nt][1], 0, 0, 0);
            agh[nt][1] = __builtin_amdgcn_mfma_f32_16x16x32_bf16(a1l, bh[nt], agh[nt][1], 0, 0, 0);
        }
        if (layer > 0) {
            bf16x8 x0h = *(const bf16x8*)(xsH + aoff);
            bf16x8 x0l = *(const bf16x8*)(xsL + aoff);
            bf16x8 x1h = *(const bf16x8*)(xsH + aoff + 128);
            bf16x8 x1l = *(const bf16x8*)(xsL + aoff + 128);
#pragma unroll
            for (int nt = 0; nt < 3; ++nt)
                bi[nt] = *(const bf16x8*)(wiH + ((size_t)kc * 48 + nt * 16 + arow) * 8);
#pragma unroll
            for (int nt = 0; nt < 3; ++nt) {
                agx[nt][0] = __builtin_amdgcn_mfma_f32_16x16x32_bf16(x0h, bi[nt], agx[nt][0], 0, 0, 0);
                agx[nt][0] = __builtin_amdgcn_mfma_f32_16x16x32_bf16(x0l, bi[nt], agx[nt][0], 0, 0, 0);
                agx[nt][1] = __builtin_amdgcn_mfma_f32_16x16x32_bf16(x1h, bi[nt], agx[nt][1], 0, 0, 0);
                agx[nt][1] = __builtin_amdgcn_mfma_f32_16x16x32_bf16(x1l, bi[nt], agx[nt][1], 0, 0, 0);
            }
        }
    }

    // merge K-partials across the 8 waves (LDS atomics)
#pragma unroll
    for (int nt = 0; nt < 3; ++nt)
#pragma unroll
        for (int m = 0; m < 2; ++m)
#pragma unroll
            for (int i = 0; i < 4; ++i)
                atomicAdd(&Cp[0][nt][m][akg * 4 + i][arow], agh[nt][m][i]);
    if (layer > 0) {
#pragma unroll
        for (int nt = 0; nt < 3; ++nt)
#pragma unroll
            for (int m = 0; m < 2; ++m)
#pragma unroll
                for (int i = 0; i < 4; ++i)
                    atomicAdd(&Cp[1][nt][m][akg * 4 + i][arow], agx[nt][m][i]);
    }
    __syncthreads();

    // Gate phase: 512 threads, one (b,u) each
    {
        const int b = tid >> 4, u = tid & 15;
        const int m = b >> 4, r = b & 15;
        const int n = n0 + u;
        float gh0 = Cp[0][0][m][r][u];
        float gh1 = Cp[0][1][m][r][u];
        float gh2 = Cp[0][2][m][r][u];
        if (layer > 0) {
            gi_0 = Cp[1][0][m][r][u] + bih[layer * H3 + n];
            gi_1 = Cp[1][1][m][r][u] + bih[layer * H3 + HD + n];
            gi_2 = Cp[1][2][m][r][u] + bih[layer * H3 + 2 * HD + n];
        }
        const float bh0 = bhh[layer * H3 + n];
        const float bh1 = bhh[layer * H3 + HD + n];
        const float bh2 = bhh[layer * H3 + 2 * HD + n];
        const float hp = hb[(size_t)(layer * 2 + (t & 1)) * BB * HD + (size_t)b * HD + n];
        float rg = 1.f / (1.f + expf(-(gi_0 + gh0 + bh0)));
        float zg = 1.f / (1.f + expf(-(gi_1 + gh1 + bh1)));
        float ng = tanhf(gi_2 + rg * (gh2 + bh2));
        float hnew = (1.f - zg) * ng + zg * hp;
        hb[(size_t)(layer * 2 + ((t + 1) & 1)) * BB * HD + (size_t)b * HD + n] = hnew;
        u16 hbits = f2bf_bits(hnew);
        u16 lbits = f2bf_bits(hnew - bf_bits2f(hbits));
        size_t o = ((size_t)(layer * 2 + ((t + 1) & 1)) * 2) * PLSZ
                 + ((size_t)(n >> 3) * 32 + b) * 8 + (n & 7);
        ht[o] = hbits;
        ht[o + PLSZ] = lbits;
        if (layer == 2) seqout[((size_t)b * TT + t) * HD + n] = hnew;
        if (t == TT - 1) hnout[(size_t)layer * BB * HD + (size_t)b * HD + n] = hnew;
    }
}

// ---------------------------------------------------------------------------
extern "C" void kernel_launch(void* const* d_in, const int* in_sizes, int n_in,
                              void* d_out, int out_size, void* d_ws, size_t ws_size,
                              hipStream_t stream) {
    const float* x   = (const float*)d_in[0];
    const float* h0  = (const float*)d_in[1];
    const float* wih = (const float*)d_in[2];
    const float* whh = (const float*)d_in[3];
    const float* bih = (const float*)d_in[4];
    const float* bhh = (const float*)d_in[5];
    float* out = (float*)d_out;

    char* ws = (char*)d_ws;
    size_t off = 0;
    auto alloc = [&](size_t bytes) -> void* {
        void* p = ws + off;
        off += (bytes + 255) & ~(size_t)255;
        return p;
    };
    // ~200 MB total
    u16* gi     = (u16*)alloc((size_t)MTOT * H3 * 2);            // 96 MB
    u16* p0h    = (u16*)alloc((size_t)MTOT * HD * 2);            // 32 MB
    u16* p0l    = (u16*)alloc((size_t)MTOT * HD * 2);            // 32 MB
    u16* wihb   = (u16*)alloc((size_t)H3 * HD * 2);              // 6.3 MB (layer0)
    u16* wslab  = (u16*)alloc((size_t)3 * 64 * WSL3 * 2);        // 18.9 MB
    u16* wislab = (u16*)alloc((size_t)2 * 64 * WSL3 * 2);        // 12.6 MB
    float* hb   = (float*)alloc((size_t)LL * 2 * BB * HD * 4);   // 786 KB
    u16* ht     = (u16*)alloc((size_t)LL * 2 * 2 * PLSZ * 2);    // 786 KB

    // setup
    split_f32_kernel<<<2048, 256, 0, stream>>>(x, p0h, p0l, MTOT * HD / 4);
    tobf_kernel<<<2048, 256, 0, stream>>>(wih, wihb, H3 * HD / 4);
    pack_w_kernel<<<192, 256, 0, stream>>>(whh, wih, wslab, wislab);
    pack_h0_kernel<<<384, 256, 0, stream>>>(h0, hb, ht);

    float* seqbase = out;                        // [B][T][H]
    float* hnbase  = out + (size_t)BB * TT * HD; // [L][B][H]

    // layer-0 input projections (one big GEMM)
    gemm2p_kernel<<<dim3(128 * 24), 256, 0, stream>>>(p0h, p0l, wihb, bih, gi);

    // pipelined recurrence: 514 step kernels
    for (int k = 0; k < TT + LL - 1; ++k)
        gru_step_kernel<<<SGRID, 512, 0, stream>>>(
            wslab, wislab, bih, bhh, gi, hb, ht, seqbase, hnbase, k);
}

// Round 14
// 6262.464 us; speedup vs baseline: 3.3773x; 3.3773x over previous
//
#include <hip/hip_runtime.h>
#include <hip/hip_bf16.h>
#include <stdint.h>

// Problem constants
#define HD   1024
#define BB   32
#define TT   512
#define LL   3
#define H3   3072
#define MTOT (BB*TT)   // 16384

#define PLSZ 32768     // u16 per h plane: 128 kc x 32 b x 8 (hi only)
#define WSL2 12288     // u16 per pad-free weight slab: 128 kc x 12 j x 8

typedef unsigned short u16;
typedef short bf16x8 __attribute__((ext_vector_type(8)));
typedef float f32x4 __attribute__((ext_vector_type(4)));

__device__ __forceinline__ u16 f2bf_bits(float f) {
    __hip_bfloat16 h = __float2bfloat16(f);   // RNE
    return __builtin_bit_cast(u16, h);
}
__device__ __forceinline__ float bf_bits2f(u16 b) {
    return __bfloat162float(__builtin_bit_cast(__hip_bfloat16, b));
}

// 8 consecutive fp32 -> bf16 hi/lo fragments
__device__ __forceinline__ void split8(const f32x4 v0, const f32x4 v1,
                                       bf16x8& hi, bf16x8& lo) {
#pragma unroll
    for (int e = 0; e < 4; ++e) {
        u16 h = f2bf_bits(v0[e]);
        hi[e] = (short)h;
        lo[e] = (short)f2bf_bits(v0[e] - bf_bits2f(h));
        u16 h2 = f2bf_bits(v1[e]);
        hi[4 + e] = (short)h2;
        lo[4 + e] = (short)f2bf_bits(v1[e] - bf_bits2f(h2));
    }
}

// ---------------------------------------------------------------------------
// Split fp32 -> (hi, lo) bf16 planes (row-major, for the big GEMM)
__global__ void split_f32_kernel(const float* __restrict__ in,
                                 u16* __restrict__ hi, u16* __restrict__ lo, int n4) {
    int i = blockIdx.x * blockDim.x + threadIdx.x;
    int stride = gridDim.x * blockDim.x;
    for (; i < n4; i += stride) {
        float4 v = ((const float4*)in)[i];
        ushort4 h, l;
        float f;
        f = v.x; h.x = f2bf_bits(f); l.x = f2bf_bits(f - bf_bits2f(h.x));
        f = v.y; h.y = f2bf_bits(f); l.y = f2bf_bits(f - bf_bits2f(h.y));
        f = v.z; h.z = f2bf_bits(f); l.z = f2bf_bits(f - bf_bits2f(h.z));
        f = v.w; h.w = f2bf_bits(f); l.w = f2bf_bits(f - bf_bits2f(h.w));
        ((ushort4*)hi)[i] = h;
        ((ushort4*)lo)[i] = l;
    }
}

// fp32 -> bf16 (hi only)
__global__ void tobf_kernel(const float* __restrict__ in, u16* __restrict__ out, int n4) {
    int i = blockIdx.x * blockDim.x + threadIdx.x;
    int stride = gridDim.x * blockDim.x;
    for (; i < n4; i += stride) {
        float4 v = ((const float4*)in)[i];
        ushort4 h;
        h.x = f2bf_bits(v.x); h.y = f2bf_bits(v.y);
        h.z = f2bf_bits(v.z); h.w = f2bf_bits(v.w);
        ((ushort4*)out)[i] = h;
    }
}

// ---------------------------------------------------------------------------
// Pack per-(layer,ug) PAD-FREE weight slabs in fragment order [kc][12][8]:
// j = gate*4 + u. whh -> hi plane; wih -> hi plane (layers 1,2).
__global__ __launch_bounds__(256) void pack_w_kernel(
    const float* __restrict__ whh, const float* __restrict__ wih,
    u16* __restrict__ wslab, u16* __restrict__ wislab)
{
    const int l  = blockIdx.x >> 8;
    const int ug = blockIdx.x & 255;
    const int n0 = ug * 4;
    const int tid = threadIdx.x;
    const int j = tid >> 4, c16 = tid & 15;
    if (j >= 12) return;
    const size_t rowoff = ((size_t)(j >> 2) * HD + n0 + (j & 3)) * HD;
    const float* wh = whh + (size_t)l * H3 * HD;
    const float* wi = wih + (size_t)l * H3 * HD;
    u16* dh = wslab + ((size_t)l * 256 + ug) * WSL2;
    u16* di = (l > 0) ? (wislab + ((size_t)(l - 1) * 256 + ug) * WSL2) : (u16*)nullptr;
#pragma unroll
    for (int c = 0; c < 8; ++c) {
        int kc = c16 + c * 16;
        f32x4 v0 = *(const f32x4*)(wh + rowoff + kc * 8);
        f32x4 v1 = *(const f32x4*)(wh + rowoff + kc * 8 + 4);
        bf16x8 hi, lo;
        split8(v0, v1, hi, lo);
        *(bf16x8*)(dh + (kc * 12 + j) * 8) = hi;
        if (l > 0) {
            f32x4 u0 = *(const f32x4*)(wi + rowoff + kc * 8);
            f32x4 u1 = *(const f32x4*)(wi + rowoff + kc * 8 + 4);
            bf16x8 ihi, dum;
            split8(u0, u1, ihi, dum);
            *(bf16x8*)(di + (kc * 12 + j) * 8) = ihi;
        }
    }
}

// h0 -> fp32 ping-pong (parity 0) + transposed bf16 hi plane (parity 0)
__global__ void pack_h0_kernel(const float* __restrict__ h0,
                               float* __restrict__ hb, u16* __restrict__ ht) {
    int idx = blockIdx.x * 256 + threadIdx.x;   // 3*32*1024 total
    int l = idx >> 15;
    int rem = idx & 32767;
    int b = rem >> 10, n = rem & 1023;
    float f = h0[idx];
    hb[(size_t)(l * 2) * BB * HD + rem] = f;
    size_t o = (size_t)(l * 2) * PLSZ + ((size_t)(n >> 3) * 32 + b) * 8 + (n & 7);
    ht[o] = f2bf_bits(f);
}

// ---------------------------------------------------------------------------
// 2-pass split-A bf16 MFMA GEMM (layer-0 input projections) — unchanged, proven.
#define BM 128
#define BN 128
#define BK 32
#define LDSROW 40

__global__ __launch_bounds__(256) void gemm2p_kernel(
    const u16* __restrict__ Ahi, const u16* __restrict__ Alo,
    const u16* __restrict__ Wn,
    const float* __restrict__ bias,
    u16* __restrict__ Cout)
{
    __shared__ u16 sAh[BM * LDSROW];
    __shared__ u16 sAl[BM * LDSROW];
    __shared__ u16 sB [BN * LDSROW];

    const int tid  = threadIdx.x;
    const int lane = tid & 63;
    const int w    = tid >> 6;
    const int wr   = w >> 1, wc = w & 1;
    const int fr   = lane & 15;
    const int kg   = lane >> 4;

    const int bm = blockIdx.x & 127;
    const int bn = blockIdx.x >> 7;
    const int bmBase = bm * BM;
    const int bnBase = bn * BN;

    f32x4 acc[4][4] = {};

    for (int kt = 0; kt < 1024; kt += BK) {
        uint4 ra[2], rl[2], rb[2];
#pragma unroll
        for (int it = 0; it < 2; ++it) {
            int c = it * 256 + tid;
            int row = c >> 2, seg = c & 3;
            size_t ga = (size_t)(bmBase + row) * 1024 + kt + seg * 8;
            ra[it] = *(const uint4*)(Ahi + ga);
            rl[it] = *(const uint4*)(Alo + ga);
            size_t gb = (size_t)(bnBase + row) * 1024 + kt + seg * 8;
            rb[it] = *(const uint4*)(Wn + gb);
        }
        __syncthreads();
#pragma unroll
        for (int it = 0; it < 2; ++it) {
            int c = it * 256 + tid;
            int row = c >> 2, seg = c & 3;
            int lo = row * LDSROW + seg * 8;
            *(uint4*)(sAh + lo) = ra[it];
            *(uint4*)(sAl + lo) = rl[it];
            *(uint4*)(sB  + lo) = rb[it];
        }
        __syncthreads();

        bf16x8 fah[4], fal[4], fb[4];
#pragma unroll
        for (int mi = 0; mi < 4; ++mi) {
            int r = wr * 64 + mi * 16 + fr;
            fah[mi] = *(const bf16x8*)(sAh + r * LDSROW + kg * 8);
            fal[mi] = *(const bf16x8*)(sAl + r * LDSROW + kg * 8);
        }
#pragma unroll
        for (int ni = 0; ni < 4; ++ni) {
            int r = wc * 64 + ni * 16 + fr;
            fb[ni] = *(const bf16x8*)(sB + r * LDSROW + kg * 8);
        }
#pragma unroll
        for (int mi = 0; mi < 4; ++mi)
#pragma unroll
            for (int ni = 0; ni < 4; ++ni) {
                acc[mi][ni] = __builtin_amdgcn_mfma_f32_16x16x32_bf16(fah[mi], fb[ni], acc[mi][ni], 0, 0, 0);
                acc[mi][ni] = __builtin_amdgcn_mfma_f32_16x16x32_bf16(fal[mi], fb[ni], acc[mi][ni], 0, 0, 0);
            }
    }

#pragma unroll
    for (int mi = 0; mi < 4; ++mi)
#pragma unroll
        for (int ni = 0; ni < 4; ++ni) {
            int n = bnBase + wc * 64 + ni * 16 + fr;
            float bv = bias[n];
#pragma unroll
            for (int r = 0; r < 4; ++r) {
                int m = bmBase + wr * 64 + mi * 16 + kg * 4 + r;
                int b_ = m >> 9, t_ = m & 511;           // m = b*512 + t
                Cout[(size_t)(t_ * BB + b_) * H3 + n] = f2bf_bits(acc[mi][ni][r] + bv);
            }
        }
}

// ---------------------------------------------------------------------------
// Pipelined per-step kernel (R12 geometry — proven best). Kernel k: layer0
// step k, layer1 k-1, layer2 k-2. Grid 768 = 3 layers x 256 ug (4 units);
// 256 threads = 4 waves (K-split 256). A-fragments are now HI-ONLY bf16
// (halves the dominant L2 A-traffic, 195->113 MB/step; h itself stays fp32
// in hb so quantization enters only through the matmuls).
#define SGRID 768

__global__ __launch_bounds__(256) void gru_step_kernel(
    const u16* __restrict__ wslab,   // [3][256][WSL2] whh hi
    const u16* __restrict__ wislab,  // [2][256][WSL2] wih hi (layers 1,2)
    const float* __restrict__ bih, const float* __restrict__ bhh,  // [L][3H]
    const u16* __restrict__ gi0,     // [T][B][3H] (layer0, incl b_ih)
    float* __restrict__ hb,          // [3][2][32][1024] fp32
    u16* __restrict__ ht,            // [3][2][PLSZ] transposed hi planes
    float* __restrict__ seqout, float* __restrict__ hnout, int k)
{
    const int layer = blockIdx.x >> 8;
    const int t = k - layer;
    if (t < 0 || t >= TT) return;
    const int ug = blockIdx.x & 255;
    const int n0 = ug * 4;
    const int tid = threadIdx.x, lane = tid & 63, w = tid >> 6;
    const int arow = lane & 15, akg = lane >> 4;

    __shared__ float Cp[4][2][2][16][16];   // [wave][src][m][row][col] 16KB

    const int xl = (layer > 0) ? layer - 1 : 0;
    const u16* hsH = ht + (size_t)(layer * 2 + (t & 1)) * PLSZ;
    const u16* xsH = ht + (size_t)(xl * 2 + ((t + 1) & 1)) * PLSZ;
    const u16* whH = wslab + ((size_t)layer * 256 + ug) * WSL2;
    const u16* wiH = wislab + ((size_t)xl * 256 + ug) * WSL2;

    // layer-0 gi early loads (latency hidden under the MFMA loop)
    float gi_0 = 0.f, gi_1 = 0.f, gi_2 = 0.f;
    if (layer == 0 && tid < 128) {
        const u16* gp = gi0 + (size_t)(t * BB + (tid >> 2)) * H3 + n0 + (tid & 3);
        gi_0 = bf_bits2f(gp[0]);
        gi_1 = bf_bits2f(gp[HD]);
        gi_2 = bf_bits2f(gp[2 * HD]);
    }

    f32x4 agh[2] = {};
    f32x4 agx[2] = {};

#pragma unroll
    for (int kt = 0; kt < 8; ++kt) {
        const int kc = w * 32 + kt * 4 + akg;
        const int aoff = (kc * 32 + arow) * 8;     // m=0; m=1 at +128
        bf16x8 a0h = *(const bf16x8*)(hsH + aoff);
        bf16x8 a1h = *(const bf16x8*)(hsH + aoff + 128);
        bf16x8 bh = {}, bi = {};
        if (arow < 12) {
            bh = *(const bf16x8*)(whH + (kc * 12 + arow) * 8);
            if (layer > 0) bi = *(const bf16x8*)(wiH + (kc * 12 + arow) * 8);
        }
        agh[0] = __builtin_amdgcn_mfma_f32_16x16x32_bf16(a0h, bh, agh[0], 0, 0, 0);
        agh[1] = __builtin_amdgcn_mfma_f32_16x16x32_bf16(a1h, bh, agh[1], 0, 0, 0);
        if (layer > 0) {
            bf16x8 x0h = *(const bf16x8*)(xsH + aoff);
            bf16x8 x1h = *(const bf16x8*)(xsH + aoff + 128);
            agx[0] = __builtin_amdgcn_mfma_f32_16x16x32_bf16(x0h, bi, agx[0], 0, 0, 0);
            agx[1] = __builtin_amdgcn_mfma_f32_16x16x32_bf16(x1h, bi, agx[1], 0, 0, 0);
        }
    }

    // Per-wave partial slices (no atomics).
#pragma unroll
    for (int m = 0; m < 2; ++m)
#pragma unroll
        for (int i = 0; i < 4; ++i)
            Cp[w][0][m][akg * 4 + i][arow] = agh[m][i];
    if (layer > 0) {
#pragma unroll
        for (int m = 0; m < 2; ++m)
#pragma unroll
            for (int i = 0; i < 4; ++i)
                Cp[w][1][m][akg * 4 + i][arow] = agx[m][i];
    }
    __syncthreads();

    // Gate phase: 128 threads, one (b,u) each
    if (tid < 128) {
        const int b = tid >> 2, u = tid & 3;
        const int m = b >> 4, r = b & 15;
        const int n = n0 + u;
        float gh0 = 0.f, gh1 = 0.f, gh2 = 0.f;
#pragma unroll
        for (int ww = 0; ww < 4; ++ww) {
            gh0 += Cp[ww][0][m][r][u];
            gh1 += Cp[ww][0][m][r][4 + u];
            gh2 += Cp[ww][0][m][r][8 + u];
        }
        if (layer > 0) {
            float q0 = 0.f, q1 = 0.f, q2 = 0.f;
#pragma unroll
            for (int ww = 0; ww < 4; ++ww) {
                q0 += Cp[ww][1][m][r][u];
                q1 += Cp[ww][1][m][r][4 + u];
                q2 += Cp[ww][1][m][r][8 + u];
            }
            gi_0 = q0 + bih[layer * H3 + n];
            gi_1 = q1 + bih[layer * H3 + HD + n];
            gi_2 = q2 + bih[layer * H3 + 2 * HD + n];
        }
        const float bh0 = bhh[layer * H3 + n];
        const float bh1 = bhh[layer * H3 + HD + n];
        const float bh2 = bhh[layer * H3 + 2 * HD + n];
        const float hp = hb[(size_t)(layer * 2 + (t & 1)) * BB * HD + (size_t)b * HD + n];
        float rg = 1.f / (1.f + expf(-(gi_0 + gh0 + bh0)));
        float zg = 1.f / (1.f + expf(-(gi_1 + gh1 + bh1)));
        float ng = tanhf(gi_2 + rg * (gh2 + bh2));
        float hnew = (1.f - zg) * ng + zg * hp;
        hb[(size_t)(layer * 2 + ((t + 1) & 1)) * BB * HD + (size_t)b * HD + n] = hnew;
        size_t o = (size_t)(layer * 2 + ((t + 1) & 1)) * PLSZ
                 + ((size_t)(n >> 3) * 32 + b) * 8 + (n & 7);
        ht[o] = f2bf_bits(hnew);
        if (layer == 2) seqout[((size_t)b * TT + t) * HD + n] = hnew;
        if (t == TT - 1) hnout[(size_t)layer * BB * HD + (size_t)b * HD + n] = hnew;
    }
}

// ---------------------------------------------------------------------------
extern "C" void kernel_launch(void* const* d_in, const int* in_sizes, int n_in,
                              void* d_out, int out_size, void* d_ws, size_t ws_size,
                              hipStream_t stream) {
    const float* x   = (const float*)d_in[0];
    const float* h0  = (const float*)d_in[1];
    const float* wih = (const float*)d_in[2];
    const float* whh = (const float*)d_in[3];
    const float* bih = (const float*)d_in[4];
    const float* bhh = (const float*)d_in[5];
    float* out = (float*)d_out;

    char* ws = (char*)d_ws;
    size_t off = 0;
    auto alloc = [&](size_t bytes) -> void* {
        void* p = ws + off;
        off += (bytes + 255) & ~(size_t)255;
        return p;
    };
    // ~200 MB total
    u16* gi     = (u16*)alloc((size_t)MTOT * H3 * 2);            // 96 MB
    u16* p0h    = (u16*)alloc((size_t)MTOT * HD * 2);            // 32 MB
    u16* p0l    = (u16*)alloc((size_t)MTOT * HD * 2);            // 32 MB
    u16* wihb   = (u16*)alloc((size_t)H3 * HD * 2);              // 6.3 MB (layer0)
    u16* wslab  = (u16*)alloc((size_t)3 * 256 * WSL2 * 2);       // 18.9 MB
    u16* wislab = (u16*)alloc((size_t)2 * 256 * WSL2 * 2);       // 12.6 MB
    float* hb   = (float*)alloc((size_t)LL * 2 * BB * HD * 4);   // 786 KB
    u16* ht     = (u16*)alloc((size_t)LL * 2 * PLSZ * 2);        // 393 KB

    // setup
    split_f32_kernel<<<2048, 256, 0, stream>>>(x, p0h, p0l, MTOT * HD / 4);
    tobf_kernel<<<2048, 256, 0, stream>>>(wih, wihb, H3 * HD / 4);
    pack_w_kernel<<<768, 256, 0, stream>>>(whh, wih, wslab, wislab);
    pack_h0_kernel<<<384, 256, 0, stream>>>(h0, hb, ht);

    float* seqbase = out;                        // [B][T][H]
    float* hnbase  = out + (size_t)BB * TT * HD; // [L][B][H]

    // layer-0 input projections (one big GEMM)
    gemm2p_kernel<<<dim3(128 * 24), 256, 0, stream>>>(p0h, p0l, wihb, bih, gi);

    // pipelined recurrence: 514 step kernels
    for (int k = 0; k < TT + LL - 1; ++k)
        gru_step_kernel<<<SGRID, 256, 0, stream>>>(
            wslab, wislab, bih, bhh, gi, hb, ht, seqbase, hnbase, k);
}